// Round 2
// baseline (319.979 us; speedup 1.0000x reference)
//
#include <hip/hip_runtime.h>

// VQ-VAE VectorQuantizer forward, fp32.
// inputs:  d_in[0] = x (64,64,32,32) NCHW fp32; d_in[1] = embedding (512,64) fp32
// outputs (concat fp32): [loss(1) | quantized NCHW (4194304) | perplexity(1) | quantized NHWC-flat (4194304)]

constexpr int DIM    = 64;
constexpr int KC     = 512;
constexpr int HW     = 1024;          // 32*32
constexpr int NPTS   = 65536;         // 64*1024
constexpr int QELEMS = NPTS * DIM;    // 4194304
constexpr int KCHUNK = 128;           // codes per wave (4 waves/block split the k-range)

// ws layout: [0..4) loss accum | [64..2112) int hist[512] | [4096..6144) float norms[512] | [8192..) int idx[65536]

__global__ void vq_norms_kernel(const float* __restrict__ emb, float* __restrict__ norms)
{
    const int k = blockIdx.x * 64 + threadIdx.x;
    const float4* row = reinterpret_cast<const float4*>(emb + (size_t)k * DIM);
    float s = 0.f;
    #pragma unroll
    for (int i = 0; i < DIM / 4; ++i) {
        float4 v = row[i];
        s = fmaf(v.x, v.x, s); s = fmaf(v.y, v.y, s);
        s = fmaf(v.z, v.z, s); s = fmaf(v.w, v.w, s);
    }
    norms[k] = s;
}

// Block = 64 points x 4 k-chunks (one chunk per wave). Codebook read straight from
// global with a wave-uniform address (scalar-load eligible) -> no LDS staging, high occupancy.
__global__ __launch_bounds__(256, 4)
void vq_argmin_kernel(const float* __restrict__ x, const float* __restrict__ emb,
                      const float* __restrict__ norms,
                      int* __restrict__ idx, int* __restrict__ hist,
                      float* __restrict__ loss_accum)
{
    __shared__ float sn[KC];
    __shared__ float sbest[4][64];
    __shared__ int   sbidx[4][64];

    const int tid  = threadIdx.x;
    const int wave = tid >> 6;      // k-chunk id
    const int lane = tid & 63;

    for (int i = tid; i < KC; i += 256) sn[i] = norms[i];
    __syncthreads();

    // point for this lane; lanes <-> consecutive hw -> coalesced strided x reads (L1-shared across the 4 waves)
    const int n  = blockIdx.x * 64 + lane;
    const int b  = n >> 10;
    const int hw = n & (HW - 1);
    const float* xp = x + (size_t)b * (DIM * HW) + hw;
    float xr[DIM];
    #pragma unroll
    for (int d = 0; d < DIM; ++d) xr[d] = xp[(size_t)d * HW];

    // argmin over this wave's chunk of ( ||e_k||^2 - 2 x.e_k )
    const int k0 = wave * KCHUNK;
    float best = 3.4e38f;
    int bestk  = k0;
    #pragma unroll 2
    for (int kk = 0; kk < KCHUNK; ++kk) {
        const int k = k0 + kk;
        const float* ek = emb + (size_t)k * DIM;   // wave-uniform address
        float a0 = 0.f, a1 = 0.f, a2 = 0.f, a3 = 0.f;
        #pragma unroll
        for (int d = 0; d < DIM; d += 4) {
            a0 = fmaf(xr[d + 0], ek[d + 0], a0);
            a1 = fmaf(xr[d + 1], ek[d + 1], a1);
            a2 = fmaf(xr[d + 2], ek[d + 2], a2);
            a3 = fmaf(xr[d + 3], ek[d + 3], a3);
        }
        float dist = sn[k] - 2.f * ((a0 + a1) + (a2 + a3));
        if (dist < best) { best = dist; bestk = k; }
    }
    sbest[wave][lane] = best;
    sbidx[wave][lane] = bestk;
    __syncthreads();

    if (wave == 0) {
        #pragma unroll
        for (int c = 1; c < 4; ++c) {
            float bc = sbest[c][lane];
            int   ic = sbidx[c][lane];
            if (bc < best) { best = bc; bestk = ic; }   // strict < keeps first occurrence on ties
        }
        idx[n] = bestk;
        atomicAdd(&hist[bestk], 1);
        // ||e_best - x||^2 = best + ||x||^2  (no codebook re-read needed)
        float xnorm = 0.f;
        #pragma unroll
        for (int d = 0; d < DIM; ++d) xnorm = fmaf(xr[d], xr[d], xnorm);
        float lsum = best + xnorm;
        #pragma unroll
        for (int off = 32; off > 0; off >>= 1)
            lsum += __shfl_down(lsum, off, 64);
        if (lane == 0) atomicAdd(loss_accum, lsum);
    }
}

// Staged transpose: coalesced emb row gather -> LDS [256][65] -> coalesced writes of both layouts.
__global__ __launch_bounds__(256)
void vq_outputs_kernel(const float* __restrict__ emb, const int* __restrict__ idx,
                       float* __restrict__ out_nchw, float* __restrict__ out_flat)
{
    __shared__ float rows[256 * 65];   // +1 pad -> conflict-free column reads
    __shared__ int   sidx[256];

    const int tid = threadIdx.x;
    const int p0  = blockIdx.x * 256;          // block's first point (256 | 1024 -> single batch b)
    sidx[tid] = idx[p0 + tid];
    __syncthreads();

    // gather 256 codebook rows, coalesced float4 (16 lanes span one row)
    const float4* esrc = reinterpret_cast<const float4*>(emb);
    #pragma unroll
    for (int i = 0; i < 16; ++i) {
        int f = tid + i * 256;                 // 0..4095
        int r = f >> 4, c = f & 15;
        float4 v = esrc[sidx[r] * (DIM / 4) + c];
        float* dst = &rows[r * 65 + c * 4];
        dst[0] = v.x; dst[1] = v.y; dst[2] = v.z; dst[3] = v.w;
    }
    __syncthreads();

    // NCHW: for fixed d, lanes <-> consecutive hw -> contiguous 1KB stores
    const int b   = p0 >> 10;
    const int hw0 = p0 & (HW - 1);
    float* op = out_nchw + (size_t)b * (DIM * HW) + hw0 + tid;
    #pragma unroll
    for (int d = 0; d < DIM; ++d)
        op[(size_t)d * HW] = rows[tid * 65 + d];

    // NHWC flat: j runs contiguously over the block's 16384 output elements
    float* of = out_flat + (size_t)p0 * DIM;
    #pragma unroll
    for (int i = 0; i < 64; ++i) {
        int j  = tid + i * 256;
        int nl = j >> 6, d = j & 63;
        of[j] = rows[nl * 65 + d];
    }
}

__global__ __launch_bounds__(512, 1)
void vq_finalize_kernel(const int* __restrict__ hist, const float* __restrict__ loss_accum,
                        float* __restrict__ out_loss, float* __restrict__ out_perp)
{
    __shared__ float wsum[8];
    const int tid = threadIdx.x;
    const float p = (float)hist[tid] * (1.0f / (float)NPTS);
    float t = p * logf(p + 1e-10f);
    #pragma unroll
    for (int off = 32; off > 0; off >>= 1)
        t += __shfl_down(t, off, 64);
    if ((tid & 63) == 0) wsum[tid >> 6] = t;
    __syncthreads();
    if (tid == 0) {
        float s = 0.f;
        #pragma unroll
        for (int w = 0; w < 8; ++w) s += wsum[w];
        *out_perp = expf(-s);
        *out_loss = (*loss_accum) * 1.25f / (float)QELEMS;   // q_latent + 0.25*e_latent, equal in fwd
    }
}

extern "C" void kernel_launch(void* const* d_in, const int* in_sizes, int n_in,
                              void* d_out, int out_size, void* d_ws, size_t ws_size,
                              hipStream_t stream)
{
    const float* x   = (const float*)d_in[0];
    const float* emb = (const float*)d_in[1];
    float* out = (float*)d_out;

    float* loss_accum = (float*)d_ws;
    int*   hist       = (int*)((char*)d_ws + 64);
    float* norms      = (float*)((char*)d_ws + 4096);
    int*   idx        = (int*)((char*)d_ws + 8192);

    hipMemsetAsync(d_ws, 0, 4096, stream);   // loss accum + histogram

    vq_norms_kernel<<<KC / 64, 64, 0, stream>>>(emb, norms);

    vq_argmin_kernel<<<NPTS / 64, 256, 0, stream>>>(x, emb, norms, idx, hist, loss_accum);

    // out[0]=loss | out[1..]=NCHW | out[1+Q]=perplexity | out[2+Q..]=NHWC flat
    vq_outputs_kernel<<<NPTS / 256, 256, 0, stream>>>(emb, idx, out + 1, out + 2 + QELEMS);

    vq_finalize_kernel<<<1, 512, 0, stream>>>(hist, loss_accum, out, out + 1 + QELEMS);
}

// Round 4
// 118.089 us; speedup vs baseline: 2.7096x; 2.7096x over previous
//
#include <hip/hip_runtime.h>

// VQ-VAE VectorQuantizer forward, fp32 in/out, MFMA (bf16-split) distance matrix.
// inputs:  d_in[0] = x (64,64,32,32) NCHW fp32; d_in[1] = embedding (512,64) fp32
// outputs (concat fp32): [loss(1) | quantized NCHW (4194304) | perplexity(1) | quantized NHWC-flat (4194304)]

constexpr int DIM    = 64;
constexpr int KC     = 512;
constexpr int HW     = 1024;
constexpr int NPTS   = 65536;
constexpr int QELEMS = NPTS * DIM;

typedef float f32x16 __attribute__((ext_vector_type(16)));
typedef short bf16x8 __attribute__((ext_vector_type(8)));

__device__ inline unsigned short f2bf(float f) {          // RNE float->bf16
    unsigned u = __float_as_uint(f);
    u += 0x7FFF + ((u >> 16) & 1);
    return (unsigned short)(u >> 16);
}
__device__ inline float bf2f(unsigned short s) { return __uint_as_float(((unsigned)s) << 16); }

__device__ inline uint4 pack8(const unsigned short* s) {
    return make_uint4((unsigned)s[0] | ((unsigned)s[1] << 16),
                      (unsigned)s[2] | ((unsigned)s[3] << 16),
                      (unsigned)s[4] | ((unsigned)s[5] << 16),
                      (unsigned)s[6] | ((unsigned)s[7] << 16));
}

// ---------------------------------------------------------------------------
// Prep: pack codebook as negated bf16 hi/lo A-fragments + norm-fold block.
// Block hb = 2*ks + hi holds, per code: shorts[j] = -e[16ks+4hi+j], shorts[4+j] = -e[16ks+8+4hi+j]
// (the 4-element-group k layout of mfma_32x32x16). hb=8: [nh,nl,0..] (norm/2 split); hb=9: zeros.
__global__ void vq_prep_kernel(const float* __restrict__ emb,
                               unsigned short* __restrict__ EH, unsigned short* __restrict__ EL)
{
    const int c = blockIdx.x * 64 + threadIdx.x;   // 0..511
    float e[DIM];
    const float4* er = reinterpret_cast<const float4*>(emb + (size_t)c * DIM);
    float nrm = 0.f;
    #pragma unroll
    for (int i = 0; i < DIM / 4; ++i) {
        float4 v = er[i];
        e[4*i+0] = v.x; e[4*i+1] = v.y; e[4*i+2] = v.z; e[4*i+3] = v.w;
        nrm = fmaf(v.x,v.x,fmaf(v.y,v.y,fmaf(v.z,v.z,fmaf(v.w,v.w,nrm))));
    }
    #pragma unroll
    for (int hb = 0; hb < 8; ++hb) {
        const int d0 = 16 * (hb >> 1) + 4 * (hb & 1);
        unsigned short hs[8], ls[8];
        #pragma unroll
        for (int j = 0; j < 4; ++j) {
            float v0 = -e[d0 + j];
            unsigned short h0 = f2bf(v0); hs[j]   = h0; ls[j]   = f2bf(v0 - bf2f(h0));
            float v1 = -e[d0 + 8 + j];
            unsigned short h1 = f2bf(v1); hs[4+j] = h1; ls[4+j] = f2bf(v1 - bf2f(h1));
        }
        *reinterpret_cast<uint4*>(EH + (size_t)(hb * KC + c) * 8) = pack8(hs);
        *reinterpret_cast<uint4*>(EL + (size_t)(hb * KC + c) * 8) = pack8(ls);
    }
    // norm fold: V = norm/2 - x.e  -> A ext dims hold bf16 split of norm/2, B ext = 1
    float nh2 = nrm * 0.5f;
    unsigned short nh = f2bf(nh2);
    unsigned short nl = f2bf(nh2 - bf2f(nh));
    unsigned short ext[8] = {nh, nl, 0,0,0,0,0,0};
    unsigned short zer[8] = {0,0,0,0,0,0,0,0};
    *reinterpret_cast<uint4*>(EH + (size_t)(8 * KC + c) * 8) = pack8(ext);
    *reinterpret_cast<uint4*>(EH + (size_t)(9 * KC + c) * 8) = pack8(zer);
}

// ---------------------------------------------------------------------------
// Main fused kernel: block = 32 points; wave w handles codes [128w,128w+128).
__global__ __launch_bounds__(256, 2)
void vq_main_kernel(const float* __restrict__ x, const float* __restrict__ emb,
                    const unsigned short* __restrict__ EH, const unsigned short* __restrict__ EL,
                    int* __restrict__ hist, float* __restrict__ loss_accum,
                    float* __restrict__ out_nchw, float* __restrict__ out_flat)
{
    __shared__ unsigned short XH[32 * 64];   // swizzled bf16-hi of X tile
    __shared__ unsigned short XL[32 * 64];   // swizzled bf16-lo
    __shared__ float sxn[8 * 32];            // per-point ||x||^2 partials
    __shared__ float wbest[4 * 32];
    __shared__ int   widx[4 * 32];
    __shared__ int   fidx[32];
    __shared__ float Qs[32 * 68];            // fp32 transpose buffer for NCHW store

    const int tid  = threadIdx.x;
    const int lane = tid & 63, w = tid >> 6;
    const int lo   = lane & 31, hi = lane >> 5;

    const int n0  = blockIdx.x * 32;
    const int b   = n0 >> 10;
    const int hw0 = n0 & (HW - 1);

    // ---- stage X tile (32 pts x 64 d) as bf16 hi/lo, 4-group quad layout + XOR swizzle
    {
        const int p = tid & 31, dg = tid >> 5;   // dg = dim-group of 8
        const float* xp = x + (size_t)b * (DIM * HW) + (size_t)(dg * 8) * HW + hw0 + p;
        float v[8]; unsigned short hs[8], ls[8];
        #pragma unroll
        for (int i = 0; i < 8; ++i) v[i] = xp[(size_t)i * HW];
        float xn = 0.f;
        #pragma unroll
        for (int i = 0; i < 8; ++i) {
            xn = fmaf(v[i], v[i], xn);
            unsigned short h = f2bf(v[i]);
            hs[i] = h; ls[i] = f2bf(v[i] - bf2f(h));
        }
        sxn[dg * 32 + p] = xn;
        // quads q0=2dg -> slot (dg&6), q1=2dg+1 -> slot (dg&6)|1 ; sub-offset 8B if dg odd
        const int s0 = dg & 6, sub = (dg & 1) * 8, sw = p & 7;
        const int b0 = p * 128 + ((s0 ^ sw) * 16) + sub;
        const int b1 = p * 128 + (((s0 | 1) ^ sw) * 16) + sub;
        uint4 ph = pack8(hs), pl = pack8(ls);
        *reinterpret_cast<uint2*>((char*)XH + b0) = make_uint2(ph.x, ph.y);
        *reinterpret_cast<uint2*>((char*)XH + b1) = make_uint2(ph.z, ph.w);
        *reinterpret_cast<uint2*>((char*)XL + b0) = make_uint2(pl.x, pl.y);
        *reinterpret_cast<uint2*>((char*)XL + b1) = make_uint2(pl.z, pl.w);
    }
    __syncthreads();

    // ---- B fragments (X side): slot = 2ks+hi, 16B read, same swizzle
    bf16x8 BH[4], BL[4];
    #pragma unroll
    for (int ks = 0; ks < 4; ++ks) {
        const int off = lo * 128 + (((2 * ks + hi) ^ (lo & 7)) * 16);
        BH[ks] = *reinterpret_cast<const bf16x8*>((const char*)XH + off);
        BL[ks] = *reinterpret_cast<const bf16x8*>((const char*)XL + off);
    }
    bf16x8 BH4 = {0,0,0,0,0,0,0,0};                     // ext dims: B[64]=B[65]=1 (hi==0, e=0,1)
    if (hi == 0) { BH4[0] = (short)0x3F80; BH4[1] = (short)0x3F80; }

    // ---- MFMA: acc = norm/2 - x.e  for 32 pts x 128 codes (4 code-tiles)
    const int c0 = w * 128;
    f32x16 a0 = {}, a1 = {}, a2 = {}, a3 = {};
    #define LOADA(arr, hb, ct) (*reinterpret_cast<const bf16x8*>((arr) + ((size_t)(hb) * KC + c0 + 32 * (ct) + lo) * 8))
    #pragma unroll
    for (int ks = 0; ks < 4; ++ks) {
        const int hb = 2 * ks + hi;
        bf16x8 ah0 = LOADA(EH, hb, 0), ah1 = LOADA(EH, hb, 1), ah2 = LOADA(EH, hb, 2), ah3 = LOADA(EH, hb, 3);
        bf16x8 al0 = LOADA(EL, hb, 0), al1 = LOADA(EL, hb, 1), al2 = LOADA(EL, hb, 2), al3 = LOADA(EL, hb, 3);
        a0 = __builtin_amdgcn_mfma_f32_32x32x16_bf16(ah0, BH[ks], a0, 0, 0, 0);
        a1 = __builtin_amdgcn_mfma_f32_32x32x16_bf16(ah1, BH[ks], a1, 0, 0, 0);
        a2 = __builtin_amdgcn_mfma_f32_32x32x16_bf16(ah2, BH[ks], a2, 0, 0, 0);
        a3 = __builtin_amdgcn_mfma_f32_32x32x16_bf16(ah3, BH[ks], a3, 0, 0, 0);
        a0 = __builtin_amdgcn_mfma_f32_32x32x16_bf16(ah0, BL[ks], a0, 0, 0, 0);
        a1 = __builtin_amdgcn_mfma_f32_32x32x16_bf16(ah1, BL[ks], a1, 0, 0, 0);
        a2 = __builtin_amdgcn_mfma_f32_32x32x16_bf16(ah2, BL[ks], a2, 0, 0, 0);
        a3 = __builtin_amdgcn_mfma_f32_32x32x16_bf16(ah3, BL[ks], a3, 0, 0, 0);
        a0 = __builtin_amdgcn_mfma_f32_32x32x16_bf16(al0, BH[ks], a0, 0, 0, 0);
        a1 = __builtin_amdgcn_mfma_f32_32x32x16_bf16(al1, BH[ks], a1, 0, 0, 0);
        a2 = __builtin_amdgcn_mfma_f32_32x32x16_bf16(al2, BH[ks], a2, 0, 0, 0);
        a3 = __builtin_amdgcn_mfma_f32_32x32x16_bf16(al3, BH[ks], a3, 0, 0, 0);
    }
    {   // 5th k-step: + (norm/2) via ext dims (hh pass only)
        const int hb = 8 + hi;
        a0 = __builtin_amdgcn_mfma_f32_32x32x16_bf16(LOADA(EH, hb, 0), BH4, a0, 0, 0, 0);
        a1 = __builtin_amdgcn_mfma_f32_32x32x16_bf16(LOADA(EH, hb, 1), BH4, a1, 0, 0, 0);
        a2 = __builtin_amdgcn_mfma_f32_32x32x16_bf16(LOADA(EH, hb, 2), BH4, a2, 0, 0, 0);
        a3 = __builtin_amdgcn_mfma_f32_32x32x16_bf16(LOADA(EH, hb, 3), BH4, a3, 0, 0, 0);
    }
    #undef LOADA

    // ---- per-lane argmin: lane holds point p=lo, codes c0+32ct+(r&3)+8*(r>>2)+4*hi
    float best = 3.4e38f; int bidx = 0;
    const int cb = c0 + 4 * hi;
    auto scan = [&](const f32x16& A, int ct) {
        #pragma unroll
        for (int r = 0; r < 16; ++r) {
            float v = A[r];
            int   c = cb + 32 * ct + (r & 3) + 8 * (r >> 2);
            if (v < best) { best = v; bidx = c; }
        }
    };
    scan(a0, 0); scan(a1, 1); scan(a2, 2); scan(a3, 3);

    {   // combine lane halves (disjoint code sets; tie -> lower index)
        float ob = __shfl_xor(best, 32, 64);
        int   oi = __shfl_xor(bidx, 32, 64);
        if (ob < best || (ob == best && oi < bidx)) { best = ob; bidx = oi; }
    }
    if (hi == 0) { wbest[w * 32 + lo] = best; widx[w * 32 + lo] = bidx; }
    __syncthreads();

    // ---- combine 4 waves (ascending code order preserves first-min), loss, hist
    if (tid < 32) {
        const int p = tid;
        float bb = wbest[p]; int bi = widx[p];
        #pragma unroll
        for (int ww = 1; ww < 4; ++ww) {
            float vb = wbest[ww * 32 + p]; int vi = widx[ww * 32 + p];
            if (vb < bb) { bb = vb; bi = vi; }
        }
        fidx[p] = bi;
        atomicAdd(&hist[bi], 1);
        float xn = 0.f;
        #pragma unroll
        for (int dg = 0; dg < 8; ++dg) xn += sxn[dg * 32 + p];
        float lsum = fmaf(2.f, bb, xn);      // ||x-e||^2 = 2*(norm/2 - x.e) + ||x||^2
        #pragma unroll
        for (int off = 16; off > 0; off >>= 1) lsum += __shfl_down(lsum, off, 32);
        if (p == 0) atomicAdd(loss_accum, lsum);
    }
    __syncthreads();

    // ---- gather winning rows, write both output layouts
    {
        const int p = tid >> 3, q = tid & 7;
        const int kidx = fidx[p];
        const float4* er = reinterpret_cast<const float4*>(emb + (size_t)kidx * DIM);
        float4 v0 = er[2 * q], v1 = er[2 * q + 1];
        // NHWC flat (base is odd*float offset -> only 8B aligned: float2 stores)
        float2* of = reinterpret_cast<float2*>(out_flat + (size_t)(n0 + p) * DIM + q * 8);
        of[0] = make_float2(v0.x, v0.y); of[1] = make_float2(v0.z, v0.w);
        of[2] = make_float2(v1.x, v1.y); of[3] = make_float2(v1.z, v1.w);
        // stage for NCHW transpose (stride 68 floats: 16B-aligned rows)
        float* qr = &Qs[p * 68 + q * 8];
        *reinterpret_cast<float4*>(qr)     = v0;
        *reinterpret_cast<float4*>(qr + 4) = v1;
    }
    __syncthreads();
    {
        const int p = tid & 31, dg = tid >> 5;
        float* op = out_nchw + (size_t)b * (DIM * HW) + (size_t)(dg * 8) * HW + hw0 + p;
        #pragma unroll
        for (int i = 0; i < 8; ++i)
            op[(size_t)i * HW] = Qs[p * 68 + dg * 8 + i];
    }
}

// ---------------------------------------------------------------------------
__global__ __launch_bounds__(512, 1)
void vq_finalize_kernel(const int* __restrict__ hist, const float* __restrict__ loss_accum,
                        float* __restrict__ out_loss, float* __restrict__ out_perp)
{
    __shared__ float wsum[8];
    const int tid = threadIdx.x;
    const float p = (float)hist[tid] * (1.0f / (float)NPTS);
    float t = p * logf(p + 1e-10f);
    #pragma unroll
    for (int off = 32; off > 0; off >>= 1)
        t += __shfl_down(t, off, 64);
    if ((tid & 63) == 0) wsum[tid >> 6] = t;
    __syncthreads();
    if (tid == 0) {
        float s = 0.f;
        #pragma unroll
        for (int w = 0; w < 8; ++w) s += wsum[w];
        *out_perp = expf(-s);
        *out_loss = (*loss_accum) * 1.25f / (float)QELEMS;   // q_latent + 0.25*e_latent (equal in fwd)
    }
}

extern "C" void kernel_launch(void* const* d_in, const int* in_sizes, int n_in,
                              void* d_out, int out_size, void* d_ws, size_t ws_size,
                              hipStream_t stream)
{
    const float* x   = (const float*)d_in[0];
    const float* emb = (const float*)d_in[1];
    float* out = (float*)d_out;

    float*          loss_accum = (float*)d_ws;
    int*            hist       = (int*)((char*)d_ws + 64);
    unsigned short* EH         = (unsigned short*)((char*)d_ws + 4096);            // 10*512*8*2 = 81920 B
    unsigned short* EL         = (unsigned short*)((char*)d_ws + 4096 + 81920);    //  8*512*8*2 = 65536 B

    hipMemsetAsync(d_ws, 0, 4096, stream);   // loss accum + histogram

    vq_prep_kernel<<<8, 64, 0, stream>>>(emb, EH, EL);

    vq_main_kernel<<<NPTS / 32, 256, 0, stream>>>(x, emb, EH, EL, hist, loss_accum,
                                                  out + 1, out + 2 + QELEMS);

    vq_finalize_kernel<<<1, 512, 0, stream>>>(hist, loss_accum, out, out + 1 + QELEMS);
}